// Round 3
// baseline (41.846 us; speedup 1.0000x reference)
//
#include <hip/hip_runtime.h>
#include <math.h>

#define LMAX   6
#define NRAD   20
#define NELEM  4
#define NBATCH 2000
#define NPTS   100000
#define NLMTOT 49            // (LMAX+1)^2
#define OUTROW 3920          // NELEM * 980
#define ACT    245           // 49 lm * 5 gn owner threads
#define PROW   72            // padded words per point in P (69 used)
#define APTS   128           // points per feat-block
#define PI_F   3.14159265358979323846f
#define RADK   0.44721359549995793f   // sqrt(2/RC), RC=10
#define INV_RC 0.1f
#define P_OFF  16384         // byte offset of P inside d_ws (seg uses first 8004 B)

// --- seg[b] = lower_bound(batch_ids, b), b in [0, NBATCH] ---
__global__ __launch_bounds__(256) void seg_kernel(
    const int* __restrict__ batch_ids, int* __restrict__ seg)
{
  int b = blockIdx.x * blockDim.x + threadIdx.x;
  if (b > NBATCH) return;
  int lo = 0, hi = NPTS;
  while (lo < hi) { int mid = (lo + hi) >> 1; if (batch_ids[mid] < b) lo = mid + 1; else hi = mid; }
  seg[b] = lo;
}

// --- dense pointwise features: P[pt][72] = {Y[49], rad[20], pad} ---
__global__ __launch_bounds__(128) void feat_kernel(
    const float* __restrict__ coords, float* __restrict__ Pg)
{
  const int blk = blockIdx.x;
  const int t = threadIdx.x;
  const int base_pt = blk * APTS;
  const int valid = min(APTS, NPTS - base_pt);

  __shared__ float sL[69][APTS + 1];   // feature-major; +1 pad -> conflict-free both phases
  __shared__ float sC[NLMTOT];

  if (t < NLMTOT) {
    int lm = t, l = 0;
    #pragma unroll
    for (int ll = 1; ll <= LMAX; ++ll) if (lm >= ll * ll) l = ll;
    int m  = lm - l * l - l;
    int am = m < 0 ? -m : m;
    float denom = 1.f;                 // (l+am)!/(l-am)!
    for (int k = l - am + 1; k <= l + am; ++k) denom *= (float)k;
    float nlm = sqrtf((float)(2 * l + 1) / denom);
    sC[lm] = (m == 0) ? nlm : 1.4142135623730951f * nlm;
  }
  __syncthreads();

  if (t < valid) {
    int p = base_pt + t;
    float x = coords[3 * p + 0], y = coords[3 * p + 1], z = coords[3 * p + 2];
    float r    = sqrtf(x * x + y * y + z * z);
    float invr = 1.f / r;
    x *= invr; y *= invr; z *= invr;

    float cs[LMAX + 1], sn[LMAX + 1];
    cs[0] = 1.f; sn[0] = 0.f;
    #pragma unroll
    for (int m = 1; m <= LMAX; ++m) {
      cs[m] = cs[m - 1] * x - sn[m - 1] * y;
      sn[m] = sn[m - 1] * x + cs[m - 1] * y;
    }
    float Q[LMAX + 1][LMAX + 1];
    Q[0][0] = 1.f;
    #pragma unroll
    for (int m = 1; m <= LMAX; ++m) Q[m][m] = -(float)(2 * m - 1) * Q[m - 1][m - 1];
    #pragma unroll
    for (int m = 0; m < LMAX; ++m) Q[m + 1][m] = (float)(2 * m + 1) * z * Q[m][m];
    #pragma unroll
    for (int m = 0; m <= LMAX; ++m) {
      #pragma unroll
      for (int ll = m + 2; ll <= LMAX; ++ll) {
        Q[ll][m] = ((float)(2 * ll - 1) * z * Q[ll - 1][m]
                  - (float)(ll + m - 1) * Q[ll - 2][m]) / (float)(ll - m);
      }
    }
    #pragma unroll
    for (int ll = 0; ll <= LMAX; ++ll) {
      #pragma unroll
      for (int m = -ll; m <= ll; ++m) {
        int am = m < 0 ? -m : m;
        float v = Q[ll][am] * sC[ll * ll + ll + m];
        if (m < 0)      v *= sn[am];
        else if (m > 0) v *= cs[am];
        sL[ll * ll + ll + m][t] = v;
      }
    }
    float a = PI_F * r * INV_RC;
    float s1, c1;
    __sincosf(a, &s1, &c1);
    float twoc = 2.f * c1;
    float sprev = 0.f, scur = s1;
    float scale = RADK * invr;
    #pragma unroll
    for (int n = 1; n <= NRAD; ++n) {
      sL[NLMTOT + n - 1][t] = scale * scur;
      float snext = twoc * scur - sprev;
      sprev = scur; scur = snext;
    }
  }
  __syncthreads();

  // coalesced float4 store of [valid][72]
  float4* out4 = (float4*)(Pg + (size_t)base_pt * PROW);
  for (int w4 = t; w4 < valid * (PROW / 4); w4 += APTS) {
    int pi = w4 / 18;
    int fj = (w4 % 18) * 4;
    float4 v;
    v.x = (fj + 0 < 69) ? sL[fj + 0][pi] : 0.f;
    v.y = (fj + 1 < 69) ? sL[fj + 1][pi] : 0.f;
    v.z = (fj + 2 < 69) ? sL[fj + 2][pi] : 0.f;
    v.w = (fj + 3 < 69) ? sL[fj + 3][pi] : 0.f;
    out4[w4] = v;
  }
}

// --- gather + segment-accumulate: one block per (batch, elem) ---
__global__ __launch_bounds__(256) void accum_kernel(
    const int*    __restrict__ elem_ids,
    const int*    __restrict__ seg,
    const float4* __restrict__ P4,
    float*        __restrict__ out)
{
  const int b = blockIdx.x >> 2;
  const int e = blockIdx.x & 3;
  const int t = threadIdx.x;

  __shared__ __align__(16) float sP[64][PROW];   // 18.4 KB
  __shared__ __align__(16) float sOut[980];
  __shared__ int sIdx[64];
  __shared__ int sMcnt;

  const int start = seg[b], end = seg[b + 1];

  const int te = (t < ACT) ? t : 0;
  const int lm = te % NLMTOT;
  const int gn = te / NLMTOT;          // 0..4
  int l = 0;
  #pragma unroll
  for (int ll = 1; ll <= LMAX; ++ll) if (lm >= ll * ll) l = ll;
  const int mi = lm - l * l;
  const int nm = 2 * l + 1;

  float acc[4] = {0.f, 0.f, 0.f, 0.f};

  for (int c = start; c < end; c += 64) {
    int cnt = end - c; if (cnt > 64) cnt = 64;

    if (t < 64) {
      bool match = (t < cnt) && (elem_ids[c + t] == e);
      unsigned long long mask = __ballot(match);
      int slot = __popcll(mask & ((1ULL << t) - 1ULL));
      if (match) sIdx[slot] = c + t;
      if (t == 0) sMcnt = __popcll(mask);
    }
    __syncthreads();
    const int mcnt = sMcnt;

    for (int w = t; w < mcnt * 18; w += 256) {
      int pi = w / 18, fi = w % 18;
      ((float4*)sP)[pi * 18 + fi] = P4[(size_t)sIdx[pi] * 18 + fi];
    }
    __syncthreads();

    if (t < ACT) {
      for (int p = 0; p < mcnt; ++p) {
        float yv = sP[p][lm];
        #pragma unroll
        for (int k = 0; k < 4; ++k)
          acc[k] += yv * sP[p][NLMTOT + gn + 5 * k];
      }
    }
    __syncthreads();
  }

  // stage 980 outputs feature-ordered, then coalesced float4 runs
  if (t < ACT) {
    int fb = 20 * l * l;
    #pragma unroll
    for (int k = 0; k < 4; ++k)
      sOut[fb + (gn + 5 * k) * nm + mi] = acc[k];
  }
  __syncthreads();

  if (t < ACT) {
    int f0 = 4 * t;
    int lw = 0;
    #pragma unroll
    for (int ll = 1; ll <= LMAX; ++ll) if (f0 >= 20 * ll * ll) lw = ll;
    int run0 = 20 * lw * lw;                       // feature offset of l-run
    long long g = (long long)b * OUTROW + 80 * lw * lw
                + (long long)e * 20 * (2 * lw + 1) + (f0 - run0);
    *(float4*)(out + g) = *(const float4*)(sOut + f0);
  }
}

extern "C" void kernel_launch(void* const* d_in, const int* in_sizes, int n_in,
                              void* d_out, int out_size, void* d_ws, size_t ws_size,
                              hipStream_t stream) {
  const float* coords    = (const float*)d_in[0];
  const int*   elem_ids  = (const int*)d_in[1];
  const int*   batch_ids = (const int*)d_in[2];
  float*       out       = (float*)d_out;
  int*         seg       = (int*)d_ws;                       // NBATCH+1 ints
  float*       Pg        = (float*)((char*)d_ws + P_OFF);    // [NPTS][72]

  seg_kernel<<<(NBATCH + 1 + 255) / 256, 256, 0, stream>>>(batch_ids, seg);
  feat_kernel<<<(NPTS + APTS - 1) / APTS, APTS, 0, stream>>>(coords, Pg);
  accum_kernel<<<NBATCH * NELEM, 256, 0, stream>>>(elem_ids, seg, (const float4*)Pg, out);
}